// Round 9
// baseline (193.595 us; speedup 1.0000x reference)
//
#include <hip/hip_runtime.h>
#include <hip/hip_bf16.h>

// TT embedding bag.
// idx = pair*50 + d2 (pair<2500, d2<50). emb depends only on idx value:
//   emb_table[idx][kk*8+z] = sum_r t[pair][kk][r] * core2[d2][r*8+z]
//   t[pair][kk=x*4+y][s]   = sum_r core0[d0][x*32+r] * core1[d1][r*128+y*32+s]
// Phase 0: chat[d2][z][r] = core2[d2][r*8+z]  (50x256 fp32, L2-hot)
// Phase A: emb_table (125000 x 128, bf16): per-pair block, LDS-transpose + coalesced store.
// Phase B: gather (addresses straight from indices) + widened LDS reduce, atomic flush.

#define PAIRS 2500
#define CHT 64    // TT positions per sum-block (256B bf16 rows)
#define CHC 32    // cached positions per sum-block (512B fp32 rows)

typedef unsigned int u32;
typedef unsigned short u16;

__device__ __forceinline__ float bflo(u32 u) { return __uint_as_float(u << 16); }
__device__ __forceinline__ float bfhi(u32 u) { return __uint_as_float(u & 0xffff0000u); }
__device__ __forceinline__ u16 f2bf(float x) {
  __hip_bfloat16 h = __float2bfloat16(x);
  return *reinterpret_cast<u16*>(&h);
}

__device__ __forceinline__ void gload_lds16(const void* g, void* l) {
  __builtin_amdgcn_global_load_lds(
      (const __attribute__((address_space(1))) u32*)g,
      (__attribute__((address_space(3))) u32*)l, 16, 0, 0);
}

// ---------------- Phase 0: core2 transpose ----------------
__global__ __launch_bounds__(256) void chat_kernel(const float* __restrict__ core2,
                                                   float* __restrict__ chat) {
  const int d2 = blockIdx.x;
  const int tid = threadIdx.x;
  const int r = tid >> 3, z = tid & 7;
  chat[d2 * 256 + z * 32 + r] = core2[d2 * 256 + r * 8 + z];
}

// ---------------- Phase A ----------------
__global__ __launch_bounds__(512, 4) void build_emb_kernel(
    const float* __restrict__ core0, const float* __restrict__ core1,
    const float* __restrict__ chat, u16* __restrict__ emb_t) {
  __shared__ float c0s[128];
  __shared__ float c1s[4096];
  __shared__ float ts[512];                  // t[kk*32+s]
  __shared__ __align__(16) u16 ebuf[6400];   // 50 rows x 128, XOR-swizzled
  const int p = blockIdx.x;
  const int d0 = p / 50, d1 = p - d0 * 50;
  const int tid = threadIdx.x;

  // stage c1 (16KB) + c0 (512B)
  {
    const float4* s1 = reinterpret_cast<const float4*>(core1 + (size_t)d1 * 4096);
    float4* dst = reinterpret_cast<float4*>(c1s);
    dst[tid] = s1[tid];
    dst[tid + 512] = s1[tid + 512];
    if (tid < 32)
      reinterpret_cast<float4*>(c0s)[tid] =
          reinterpret_cast<const float4*>(core0 + (size_t)d0 * 128)[tid];
  }

  // chat column prefetch into regs (independent of LDS; consumed after barrier 2)
  const int d2 = tid >> 3, z = tid & 7;
  float4 c[8];
  if (tid < 400) {
    const float4* cp = reinterpret_cast<const float4*>(chat + d2 * 256 + z * 32);
#pragma unroll
    for (int rq = 0; rq < 8; ++rq) c[rq] = cp[rq];
  }
  __syncthreads();

  // t = 16x32, one element per thread (512 threads, 512 elements)
  {
    const int kk = tid >> 5, s = tid & 31;
    const int x = kk >> 2, y = kk & 3;
    float acc = 0.f;
#pragma unroll
    for (int r = 0; r < 32; ++r)
      acc += c0s[x * 32 + r] * c1s[r * 128 + y * 32 + s];
    ts[kk * 32 + s] = acc;
  }
  __syncthreads();

  // GEMM2: thread (d2,z) computes 16 outputs, writes swizzled u16 into ebuf
  if (tid < 400) {
    const float4* t4 = reinterpret_cast<const float4*>(ts);
    const u32 sw = ((u32)(d2 & 7)) << 4;
#pragma unroll
    for (int kk = 0; kk < 16; ++kk) {
      float s = 0.f;
#pragma unroll
      for (int rq = 0; rq < 8; ++rq) {
        const float4 tb = t4[kk * 8 + rq];   // wave-uniform -> LDS broadcast
        s += tb.x * c[rq].x + tb.y * c[rq].y + tb.z * c[rq].z + tb.w * c[rq].w;
      }
      const u32 byte = (u32)d2 * 256 + (u32)kk * 16 + (u32)z * 2;
      *reinterpret_cast<u16*>(reinterpret_cast<char*>(ebuf) + (byte ^ sw)) = f2bf(s);
    }
  }
  __syncthreads();

  // coalesced store: 1600 uint2 (12.8KB) with inverse swizzle on the LDS read
  {
    uint2* gdst = reinterpret_cast<uint2*>(emb_t + (size_t)p * 6400);
    for (int e = tid; e < 1600; e += 512) {
      const u32 byte = (u32)e * 8;
      const u32 swb = byte ^ ((((byte >> 8) & 7)) << 4);
      gdst[e] = *reinterpret_cast<const uint2*>(
          reinterpret_cast<const char*>(ebuf) + swb);
    }
  }
}

// ---------------- Phase B ----------------
__device__ __forceinline__ int bag_search(const int* __restrict__ offs,
                                          int nbags, int p) {
  int lo = 0, hi = nbags;
  while (hi - lo > 1) {
    int m = (lo + hi) >> 1;
    if (offs[m] <= p) lo = m; else hi = m;
  }
  return lo;
}

__global__ __launch_bounds__(256, 8) void sum_kernel(
    const int* __restrict__ indices, const int* __restrict__ offsets,
    const int* __restrict__ cached_indices, const int* __restrict__ cached_offsets,
    const float* __restrict__ cache_table, const u16* __restrict__ emb_t,
    float* __restrict__ out, int n, int nbags, int ntt_blocks) {
  __shared__ __align__(16) u16 sdat[CHT * 128];  // 16KB (cache part: float[CHC*128])
  __shared__ int sbag[CHT];
  __shared__ int sbb[CHT];                       // (bag<<1) | boundary
  const int tid = threadIdx.x;
  const int bid = blockIdx.x;
  const int lane = tid & 63;
  const int w = tid >> 6;

  if (bid < ntt_blocks) {
    // ---- TT: gather 256B bf16 rows; addresses straight from indices ----
    const int base = bid * CHT;
    const int count = min(CHT, n - base);
    if (count == CHT) {
      u32* ldsb = reinterpret_cast<u32*>(sdat);
#pragma unroll
      for (int j = 0; j < 4; ++j) {
        const int r4 = w * 16 + j * 4;
        const int row = r4 + (lane >> 4);
        const int gidx = indices[base + row];
        const char* src = reinterpret_cast<const char*>(emb_t) +
                          (((size_t)gidx) << 8) + ((lane & 15) << 4);
        gload_lds16(src, ldsb + r4 * 64);
      }
    } else {
      for (int r = w; r < count; r += 4) {
        const int gidx = indices[base + r];
        reinterpret_cast<u32*>(sdat)[r * 64 + lane] =
            reinterpret_cast<const u32*>(emb_t)[(((size_t)gidx) << 6) + lane];
      }
    }
    if (tid < count) sbag[tid] = bag_search(offsets, nbags, base + tid);
    __syncthreads();
    if (tid < count)
      sbb[tid] = (sbag[tid] << 1) |
                 ((tid + 1 == count || sbag[tid + 1] != sbag[tid]) ? 1 : 0);
    __syncthreads();

    const int kp = tid & 63, h = tid >> 6;
    const int rlo = h * 16, rhi = min(count, rlo + 16);
    float a0 = 0.f, a1 = 0.f;
    for (int i = rlo; i < rhi; ++i) {
      const u32 v = *reinterpret_cast<const u32*>(sdat + (size_t)i * 128 + kp * 2);
      const int bb = sbb[i];
      a0 += bflo(v); a1 += bfhi(v);
      if ((bb & 1) || (i + 1 == rhi)) {
        float* o = out + (((size_t)(bb >> 1)) << 7) + kp * 2;
        atomicAdd(o, a0); atomicAdd(o + 1, a1);
        a0 = 0.f; a1 = 0.f;
      }
    }
  } else {
    // ---- cache: gather 512B fp32 rows ----
    const int cb = bid - ntt_blocks;
    const int base = cb * CHC;
    const int count = min(CHC, n - base);
    float* sfl = reinterpret_cast<float*>(sdat);
    if (count == CHC) {
#pragma unroll
      for (int j = 0; j < 4; ++j) {
        const int r2 = w * 8 + j * 2;
        const int row = r2 + (lane >> 5);
        const int gidx = cached_indices[base + row];
        const char* src = reinterpret_cast<const char*>(cache_table) +
                          (((size_t)gidx) << 9) + ((lane & 31) << 4);
        gload_lds16(src, sfl + r2 * 128);
      }
    } else {
      for (int r = w; r < count; r += 4) {
        const int gidx = cached_indices[base + r];
        reinterpret_cast<float2*>(sfl + r * 128)[lane] =
            reinterpret_cast<const float2*>(cache_table + (((size_t)gidx) << 7))[lane];
      }
    }
    if (tid < count) sbag[tid] = bag_search(cached_offsets, nbags, base + tid);
    __syncthreads();
    if (tid < count)
      sbb[tid] = (sbag[tid] << 1) |
                 ((tid + 1 == count || sbag[tid + 1] != sbag[tid]) ? 1 : 0);
    __syncthreads();

    const int kp = tid & 63, h = tid >> 6;
    const int rlo = h * 8, rhi = min(count, rlo + 8);
    float a0 = 0.f, a1 = 0.f;
    for (int i = rlo; i < rhi; ++i) {
      const float2 v = *reinterpret_cast<const float2*>(sfl + (size_t)i * 128 + kp * 2);
      const int bb = sbb[i];
      a0 += v.x; a1 += v.y;
      if ((bb & 1) || (i + 1 == rhi)) {
        float* o = out + (((size_t)(bb >> 1)) << 7) + kp * 2;
        atomicAdd(o, a0); atomicAdd(o + 1, a1);
        a0 = 0.f; a1 = 0.f;
      }
    }
  }
}

extern "C" void kernel_launch(void* const* d_in, const int* in_sizes, int n_in,
                              void* d_out, int out_size, void* d_ws, size_t ws_size,
                              hipStream_t stream) {
  const int* indices        = (const int*)d_in[0];
  const int* offsets        = (const int*)d_in[1];
  const int* cached_indices = (const int*)d_in[2];
  const int* cached_offsets = (const int*)d_in[3];
  const float* core0        = (const float*)d_in[4];
  const float* core1        = (const float*)d_in[5];
  const float* core2        = (const float*)d_in[6];
  const float* cache_table  = (const float*)d_in[7];
  float* out = (float*)d_out;

  const int n = in_sizes[0];             // 204800
  const int nbags = in_sizes[1] - 1;     // 4096

  u16* emb_t = (u16*)d_ws;                                   // 32,000,000 B
  float* chat = (float*)((char*)d_ws + 32000000);            // 51,200 B

  hipMemsetAsync(out, 0, (size_t)out_size * sizeof(float), stream);

  chat_kernel<<<50, 256, 0, stream>>>(core2, chat);
  build_emb_kernel<<<PAIRS, 512, 0, stream>>>(core0, core1, chat, emb_t);

  const int ntt = (n + CHT - 1) / CHT;   // 3200
  const int nc  = (n + CHC - 1) / CHC;   // 6400
  sum_kernel<<<ntt + nc, 256, 0, stream>>>(
      indices, offsets, cached_indices, cached_offsets, cache_table, emb_t,
      out, n, nbags, ntt);
}

// Round 11
// 171.792 us; speedup vs baseline: 1.1269x; 1.1269x over previous
//
#include <hip/hip_runtime.h>
#include <hip/hip_bf16.h>

// TT embedding bag.
// idx = pair*50 + d2 (pair<2500, d2<50). emb depends only on idx value:
//   emb_table[idx][kk*8+z] = sum_r t[pair][kk][r] * core2[d2][r*8+z]
//   t[pair][kk=x*4+y][s]   = sum_r core0[d0][x*32+r] * core1[d1][r*128+y*32+s]
// Phase 0: chat[d2][z][r] = core2[d2][r*8+z]  (50x256 fp32, L2-hot)
// Phase A: emb_table (125000 x 128, bf16): per-pair 128-thread block; GEMM2 with
//          4 output columns per thread (amortizes LDS broadcast reads of t 3.5x),
//          direct packed uint2 stores.
// Phase B: LDS-staged gathers + segmented sum (round-7 structure: contiguous
//          single-atomic flush per 64-lane wave), 8 blocks/CU.

#define PAIRS 2500
#define CHT 64    // TT positions per sum-block (256B bf16 rows)
#define CHC 32    // cached positions per sum-block (512B fp32 rows)

typedef unsigned int u32;
typedef unsigned short u16;

__device__ __forceinline__ float bfu(u16 u) { return __uint_as_float(((u32)u) << 16); }
__device__ __forceinline__ u16 f2bf(float x) {
  __hip_bfloat16 h = __float2bfloat16(x);
  return *reinterpret_cast<u16*>(&h);
}
__device__ __forceinline__ u32 pack2bf(float lo, float hi) {
  return ((u32)f2bf(hi) << 16) | (u32)f2bf(lo);
}

__device__ __forceinline__ void gload_lds16(const void* g, void* l) {
  __builtin_amdgcn_global_load_lds(
      (const __attribute__((address_space(1))) u32*)g,
      (__attribute__((address_space(3))) u32*)l, 16, 0, 0);
}

// ---------------- Phase 0: core2 transpose ----------------
__global__ __launch_bounds__(256) void chat_kernel(const float* __restrict__ core2,
                                                   float* __restrict__ chat) {
  const int d2 = blockIdx.x;
  const int tid = threadIdx.x;          // tid = r*8+z
  const int r = tid >> 3, z = tid & 7;
  chat[d2 * 256 + z * 32 + r] = core2[d2 * 256 + tid];
}

// ---------------- Phase A ----------------
__global__ __launch_bounds__(128) void build_emb_kernel(
    const float* __restrict__ core0, const float* __restrict__ core1,
    const float* __restrict__ chat, u16* __restrict__ emb_t) {
  __shared__ float c0s[128];
  __shared__ float c1s[4096];
  __shared__ float ts[512];            // t[kk*32+s]
  const int p = blockIdx.x;
  const int d0 = p / 50, d1 = p - d0 * 50;
  const int tid = threadIdx.x;

  // chat columns (d2, z=zg*4+j, j=0..3) prefetch into regs (L2; no LDS dep)
  const int d2 = tid >> 1, zg = tid & 1;
  float4 c[4][8];
  if (tid < 100) {
#pragma unroll
    for (int j = 0; j < 4; ++j) {
      const float4* cp =
          reinterpret_cast<const float4*>(chat + d2 * 256 + (zg * 4 + j) * 32);
#pragma unroll
      for (int rq = 0; rq < 8; ++rq) c[j][rq] = cp[rq];
    }
  }

  // stage c1 (16KB) + c0 (512B)
  {
    const float4* s1 = reinterpret_cast<const float4*>(core1 + (size_t)d1 * 4096);
    float4* dst = reinterpret_cast<float4*>(c1s);
#pragma unroll
    for (int i = 0; i < 8; ++i) dst[tid + i * 128] = s1[tid + i * 128];
    if (tid < 32)
      reinterpret_cast<float4*>(c0s)[tid] =
          reinterpret_cast<const float4*>(core0 + (size_t)d0 * 128)[tid];
  }
  __syncthreads();

  // t = 16x32: thread computes 4 consecutive elements (float4)
  {
    const int kk = tid >> 3, s0 = (tid & 7) * 4;
    const int x = kk >> 2, y = kk & 3;
    float4 acc = make_float4(0.f, 0.f, 0.f, 0.f);
#pragma unroll
    for (int r = 0; r < 32; ++r) {
      const float a = c0s[x * 32 + r];
      const float4 b = *reinterpret_cast<const float4*>(c1s + r * 128 + y * 32 + s0);
      acc.x += a * b.x; acc.y += a * b.y; acc.z += a * b.z; acc.w += a * b.w;
    }
    *reinterpret_cast<float4*>(ts + tid * 4) = acc;
  }
  __syncthreads();

  // GEMM2: thread (d2, zg) -> 4 columns; t rows via wave-uniform LDS broadcast
  if (tid < 100) {
    const float4* t4 = reinterpret_cast<const float4*>(ts);
    uint2* orow = reinterpret_cast<uint2*>(emb_t + (((size_t)(p * 50 + d2)) << 7));
#pragma unroll
    for (int kk = 0; kk < 16; ++kk) {
      float s0 = 0.f, s1 = 0.f, s2 = 0.f, s3 = 0.f;
#pragma unroll
      for (int rq = 0; rq < 8; ++rq) {
        const float4 tb = t4[kk * 8 + rq];   // broadcast: 1 read serves 64 lanes
        s0 += tb.x * c[0][rq].x + tb.y * c[0][rq].y + tb.z * c[0][rq].z + tb.w * c[0][rq].w;
        s1 += tb.x * c[1][rq].x + tb.y * c[1][rq].y + tb.z * c[1][rq].z + tb.w * c[1][rq].w;
        s2 += tb.x * c[2][rq].x + tb.y * c[2][rq].y + tb.z * c[2][rq].z + tb.w * c[2][rq].w;
        s3 += tb.x * c[3][rq].x + tb.y * c[3][rq].y + tb.z * c[3][rq].z + tb.w * c[3][rq].w;
      }
      orow[kk * 2 + zg] = make_uint2(pack2bf(s0, s1), pack2bf(s2, s3));
    }
  }
}

// ---------------- Phase B (round-7 structure) ----------------
__device__ __forceinline__ int bag_search(const int* __restrict__ offs,
                                          int nbags, int p) {
  int lo = 0, hi = nbags;
  while (hi - lo > 1) {
    int m = (lo + hi) >> 1;
    if (offs[m] <= p) lo = m; else hi = m;
  }
  return lo;
}

__global__ __launch_bounds__(256, 8) void sum_kernel(
    const int* __restrict__ indices, const int* __restrict__ offsets,
    const int* __restrict__ cached_indices, const int* __restrict__ cached_offsets,
    const float* __restrict__ cache_table, const u16* __restrict__ emb_t,
    float* __restrict__ out, int n, int nbags, int ntt_blocks) {
  __shared__ __align__(16) u16 sdat[CHT * 128];  // 16KB; cache part uses float[CHC*128]
  __shared__ int sidx[CHT];
  __shared__ int sbag[CHT];
  const int tid = threadIdx.x;
  const int bid = blockIdx.x;
  const int lane = tid & 63;
  const int w = tid >> 6;

  if (bid < ntt_blocks) {
    // ---- TT gather: 256B bf16 rows from emb_table ----
    const int base = bid * CHT;
    const int count = min(CHT, n - base);
    if (tid < count) {
      sidx[tid] = indices[base + tid];
      sbag[tid] = bag_search(offsets, nbags, base + tid);
    }
    __syncthreads();
    if (count == CHT) {
      u32* ldsb = reinterpret_cast<u32*>(sdat);
#pragma unroll
      for (int j = 0; j < 4; ++j) {
        const int r4 = w * 16 + j * 4;                 // 4 rows per instruction
        const int row = r4 + (lane >> 4);
        const char* src = reinterpret_cast<const char*>(emb_t) +
                          (((size_t)sidx[row]) << 8) + ((lane & 15) << 4);
        gload_lds16(src, ldsb + r4 * 64);
      }
    } else {
      for (int r = w; r < count; r += 4) {
        reinterpret_cast<u32*>(sdat)[r * 64 + lane] =
            reinterpret_cast<const u32*>(emb_t)[(((size_t)sidx[r]) << 6) + lane];
      }
    }
    __syncthreads();
    const int k = tid & 127, h = tid >> 7;
    const int rlo = h * (CHT / 2);
    const int rhi = min(count, rlo + CHT / 2);
    float acc = 0.f;
    for (int i = rlo; i < rhi; ++i) {
      acc += bfu(sdat[i * 128 + k]);
      if (i + 1 == rhi || sbag[i + 1] != sbag[i]) {
        atomicAdd(out + (((size_t)sbag[i]) << 7) + k, acc);
        acc = 0.f;
      }
    }
  } else {
    // ---- cache gather: 512B fp32 rows from cache_table ----
    const int cb = bid - ntt_blocks;
    const int base = cb * CHC;
    const int count = min(CHC, n - base);
    float* sfl = reinterpret_cast<float*>(sdat);
    if (tid < count) {
      sidx[tid] = cached_indices[base + tid];
      sbag[tid] = bag_search(cached_offsets, nbags, base + tid);
    }
    __syncthreads();
    if (count == CHC) {
#pragma unroll
      for (int j = 0; j < 4; ++j) {
        const int r2 = w * 8 + j * 2;                  // 2 rows per instruction
        const int row = r2 + (lane >> 5);
        const char* src = reinterpret_cast<const char*>(cache_table) +
                          (((size_t)sidx[row]) << 9) + ((lane & 31) << 4);
        gload_lds16(src, sfl + r2 * 128);
      }
    } else {
      for (int r = w; r < count; r += 4) {
        reinterpret_cast<float2*>(sfl + r * 128)[lane] =
            reinterpret_cast<const float2*>(cache_table + (((size_t)sidx[r]) << 7))[lane];
      }
    }
    __syncthreads();
    const int k = tid & 127, h = tid >> 7;
    const int rlo = h * (CHC / 2);
    const int rhi = min(count, rlo + CHC / 2);
    float acc = 0.f;
    for (int i = rlo; i < rhi; ++i) {
      acc += sfl[i * 128 + k];
      if (i + 1 == rhi || sbag[i + 1] != sbag[i]) {
        atomicAdd(out + (((size_t)sbag[i]) << 7) + k, acc);
        acc = 0.f;
      }
    }
  }
}

extern "C" void kernel_launch(void* const* d_in, const int* in_sizes, int n_in,
                              void* d_out, int out_size, void* d_ws, size_t ws_size,
                              hipStream_t stream) {
  const int* indices        = (const int*)d_in[0];
  const int* offsets        = (const int*)d_in[1];
  const int* cached_indices = (const int*)d_in[2];
  const int* cached_offsets = (const int*)d_in[3];
  const float* core0        = (const float*)d_in[4];
  const float* core1        = (const float*)d_in[5];
  const float* core2        = (const float*)d_in[6];
  const float* cache_table  = (const float*)d_in[7];
  float* out = (float*)d_out;

  const int n = in_sizes[0];             // 204800
  const int nbags = in_sizes[1] - 1;     // 4096

  u16* emb_t = (u16*)d_ws;                                   // 32,000,000 B
  float* chat = (float*)((char*)d_ws + 32000000);            // 51,200 B

  hipMemsetAsync(out, 0, (size_t)out_size * sizeof(float), stream);

  chat_kernel<<<50, 256, 0, stream>>>(core2, chat);
  build_emb_kernel<<<PAIRS, 128, 0, stream>>>(core0, core1, chat, emb_t);

  const int ntt = (n + CHT - 1) / CHT;   // 3200
  const int nc  = (n + CHC - 1) / CHC;   // 6400
  sum_kernel<<<ntt + nc, 256, 0, stream>>>(
      indices, offsets, cached_indices, cached_offsets, cache_table, emb_t,
      out, n, nbags, ntt);
}